// Round 17
// baseline (1180.931 us; speedup 1.0000x reference)
//
#include <hip/hip_runtime.h>
#include <hip/hip_bf16.h>
#include <hip/hip_cooperative_groups.h>

namespace cg = cooperative_groups;

#define HD 768
#define N_NODES 16383
#define NLEAF_OFF 8191     // first leaf node index (level d=13 offset)
#define NHF 12582144       // N_NODES * HD
#define TEMP 3.0f

using bf16 = __hip_bfloat16;
typedef __attribute__((ext_vector_type(8))) short bf16x8;
typedef __attribute__((ext_vector_type(4))) float f32x4;

__device__ __forceinline__ float sigm(float x) { return 1.0f / (1.0f + __expf(-x)); }
__device__ __forceinline__ float b2f(bf16 v)   { return __bfloat162float(v); }
__device__ __forceinline__ bf16  f2b(float v)  { return __float2bfloat16(v); }

// async global->LDS, 16B per lane. LDS dest = wave-uniform base + lane*16.
__device__ __forceinline__ void gload16(const void* g, void* l) {
    __builtin_amdgcn_global_load_lds(
        (const __attribute__((address_space(1))) unsigned int*)g,
        (__attribute__((address_space(3))) unsigned int*)l, 16, 0, 0);
}

#define T1SZ 5898240      // 3840*1536
#define T2SZ 10616832     // 4608*2304
#define WSZ  589824       // 768*768

// ---------------------------------------------------------------------------
// Tiled transpose-convert (R11-proven): BT1, BT2, W1T, coalesced both sides.
// ---------------------------------------------------------------------------
__global__ __launch_bounds__(256) void tconv_k(
    const float* __restrict__ Ub_iou, const float* __restrict__ Ub_f,
    const float* __restrict__ Ut_iou, const float* __restrict__ Ut_f,
    const float* __restrict__ ffn_W1,
    bf16* __restrict__ BT1, bf16* __restrict__ BT2, bf16* __restrict__ W1T)
{
    int t = blockIdx.x;
    const float* src; bf16* dst; int C, S, kt, nt;
    if (t < 3456) {
        src = Ub_iou; dst = BT1; C = 2304; S = 1536;
        kt = t % 48; nt = t / 48;
    } else if (t < 5760) {
        int u = t - 3456; int piece = u / 576; u -= piece * 576;
        int kk = piece >> 1, l = piece & 1;
        src = Ub_f + (size_t)(kk * 2 + l) * WSZ;
        dst = BT1 + (size_t)(2304 + kk * 768) * 1536 + l * 768;
        C = 768; S = 1536; kt = u % 24; nt = u / 24;
    } else if (t < 10944) {
        int u = t - 5760;
        src = Ut_iou; dst = BT2; C = 2304; S = 2304;
        kt = u % 72; nt = u / 72;
    } else if (t < 16128) {
        int u = t - 10944; int piece = u / 576; u -= piece * 576;
        int kk = piece / 3, l = piece - kk * 3;
        src = Ut_f + (size_t)(kk * 3 + l) * WSZ;
        dst = BT2 + (size_t)(2304 + kk * 768) * 2304 + l * 768;
        C = 768; S = 2304; kt = u % 24; nt = u / 24;
    } else {
        int u = t - 16128;
        src = ffn_W1; dst = W1T; C = 768; S = 768;
        kt = u % 24; nt = u / 24;
    }
    int k0 = kt * 32, n0 = nt * 32;

    __shared__ float tl[32][33];
    int rr = threadIdx.x >> 5, c = threadIdx.x & 31;
#pragma unroll
    for (int r = 0; r < 32; r += 8)
        tl[rr + r][c] = src[(size_t)(k0 + rr + r) * C + n0 + c];
    __syncthreads();
#pragma unroll
    for (int r = 0; r < 32; r += 8)
        dst[(size_t)(n0 + rr + r) * S + k0 + c] = f2b(tl[c][rr + r]);
}

// ---------------------------------------------------------------------------
// Misc converts: WhT[128][768] + W2 bf16 cast.
// ---------------------------------------------------------------------------
#define HSZ2 98304        // 128*768
__global__ __launch_bounds__(256) void misc_k(
    const float* __restrict__ hlW, const float* __restrict__ intW,
    const float* __restrict__ actW, const float* __restrict__ W2,
    bf16* __restrict__ WhT, bf16* __restrict__ W2b)
{
    int idx = blockIdx.x * 256 + threadIdx.x;
    if (idx < HSZ2) {
        int n = idx / 768, j = idx - n * 768;
        float v = 0.f;
        if (n < 2)       v = hlW[(size_t)j * 2 + n];
        else if (n < 4)  v = intW[(size_t)j * 2 + (n - 2)];
        else if (n < 68) v = actW[(size_t)j * 64 + (n - 4)];
        WhT[idx] = f2b(v);
    } else if (idx < HSZ2 + WSZ) {
        int i2 = idx - HSZ2;
        W2b[i2] = f2b(W2[i2]);
    }
}

// Fused bias: bc[n] = sum_j b2[j]*Wh[j][n] + head_bias(n).
__global__ __launch_bounds__(128) void bck_k(
    const float* __restrict__ b2,
    const float* __restrict__ hlW, const float* __restrict__ hlb,
    const float* __restrict__ intW, const float* __restrict__ intb,
    const float* __restrict__ actW, const float* __restrict__ actb,
    float* __restrict__ bc)
{
    int n = threadIdx.x;
    float s = 0.f;
    for (int j = 0; j < 768; ++j) {
        float wh = 0.f;
        if (n < 2)       wh = hlW[(size_t)j * 2 + n];
        else if (n < 4)  wh = intW[(size_t)j * 2 + (n - 2)];
        else if (n < 68) wh = actW[(size_t)j * 64 + (n - 4)];
        s = fmaf(b2[j], wh, s);
    }
    float hb = 0.f;
    if (n < 2)       hb = hlb[n];
    else if (n < 4)  hb = intb[n - 2];
    else if (n < 68) hb = actb[n - 4];
    bc[n] = s + hb;
}

// ---------------------------------------------------------------------------
// Vocab precompute + leaf scatter (R16-proven).
// ---------------------------------------------------------------------------
__global__ __launch_bounds__(256) void vocab_k(
    const float* __restrict__ Wb, const float* __restrict__ bb,
    const float* __restrict__ Wt, const float* __restrict__ bt,
    bf16* __restrict__ Vh, bf16* __restrict__ Vc, bf16* __restrict__ Vh3)
{
    int idx = blockIdx.x * 256 + threadIdx.x;
    if (idx >= 512 * HD) return;
    int id = idx / HD, j = idx - id * HD;
    const float* w = Wb + (size_t)id * 3 * HD;
    float iv = sigm(w[j] + bb[j]);
    float ov = sigm(w[HD + j] + bb[HD + j]);
    float gv = tanhf(w[2 * HD + j] + bb[2 * HD + j]);
    float c = iv * gv;
    Vh[idx] = f2b(ov * tanhf(c));
    Vc[idx] = f2b(c);

    const float* w2 = Wt + (size_t)id * 3 * HD;
    float iv2 = sigm(w2[j] + bt[j]);
    float ov2 = sigm(w2[HD + j] + bt[HD + j]);
    float gv2 = tanhf(w2[2 * HD + j] + bt[2 * HD + j]);
    float c2 = iv2 * gv2;
    Vh3[idx] = f2b(ov2 * tanhf(c2));
}

__global__ __launch_bounds__(256) void lscat_k(
    const int* __restrict__ ids,
    const bf16* __restrict__ Vh, const bf16* __restrict__ Vc,
    const bf16* __restrict__ Vh3,
    bf16* __restrict__ h_all, bf16* __restrict__ c_all, bf16* __restrict__ h3_all)
{
    int idx = blockIdx.x * 256 + threadIdx.x;
    if (idx >= 8192 * 96) return;
    int i = idx / 96, j8 = (idx - i * 96) * 8;
    int g = NLEAF_OFF + i;
    size_t so = (size_t)ids[g] * HD + j8;
    size_t dof = (size_t)g * HD + j8;
    *(uint4*)(h_all + dof)  = *(const uint4*)(Vh + so);
    *(uint4*)(c_all + dof)  = *(const uint4*)(Vc + so);
    *(uint4*)(h3_all + dof) = *(const uint4*)(Vh3 + so);
}

// ---------------------------------------------------------------------------
// COOPERATIVE tail kernel: all levels d=8..0 in ONE launch.
// 120 blocks x 512 thr (960 waves), no LDS -> co-residency guaranteed.
// Per level: phase A = 16x64 MFMA wave-tiles, frags loaded DIRECTLY from
// global (L2-hot; A-frag row=lane&15, k=(lane>>4)*8 — same mapping as mm_k),
// K split z={0,1} (768 each) into fp32 partials Sf[z][256][3840];
// grid.sync(); phase B = cell (KS=2 partial sum); grid.sync().
// ---------------------------------------------------------------------------
__global__ __launch_bounds__(512) void tail_k(
    const int* __restrict__ ids,
    bf16* __restrict__ h_all, bf16* __restrict__ c_all,
    const bf16* __restrict__ BT1,
    const float* __restrict__ Wiou, const float* __restrict__ biou,
    const float* __restrict__ Wf, const float* __restrict__ bfv,
    float* __restrict__ Sf)
{
    cg::grid_group grid = cg::this_grid();
    const int lane = threadIdx.x & 63;
    const int gw = (blockIdx.x * 512 + threadIdx.x) >> 6;   // 0..959
    const int gt = blockIdx.x * 512 + threadIdx.x;          // 0..61439

    const int fr = lane & 15;
    const int fk = (lane >> 4) << 3;

    for (int d = 8; d >= 0; --d) {
        const int n = 1 << d, off = n - 1, childoff = 2 * n - 1;
        const bf16* A = h_all + (size_t)childoff * HD;      // rows of 1536
        const int rowTiles = (n + 15) >> 4;
        const int tilesPerZ = rowTiles * 60;
        const int tiles = tilesPerZ * 2;

        // ---- phase A: GEMM partials ----
        for (int t = gw; t < tiles; t += 960) {
            int z = t / tilesPerZ;
            int rem = t - z * tilesPerZ;
            int rt = rem / 60, ct = rem - rt * 60;
            int r0 = rt * 16, c0 = ct * 64;
            int arow = r0 + fr;
            if (arow > n - 1) arow = n - 1;
            const bf16* Ap = A + (size_t)arow * 1536 + z * 768 + fk;
            const bf16* Bp0 = BT1 + (size_t)(c0 + fr) * 1536 + z * 768 + fk;

            f32x4 acc[4] = {};
            for (int kt = 0; kt < 768; kt += 32) {
                bf16x8 av = *(const bf16x8*)(Ap + kt);
#pragma unroll
                for (int f = 0; f < 4; ++f) {
                    bf16x8 bv = *(const bf16x8*)(Bp0 + (size_t)f * 16 * 1536 + kt);
                    acc[f] = __builtin_amdgcn_mfma_f32_16x16x32_bf16(
                        av, bv, acc[f], 0, 0, 0);
                }
            }
            int drow = r0 + ((lane >> 4) << 2);
#pragma unroll
            for (int f = 0; f < 4; ++f)
#pragma unroll
                for (int r = 0; r < 4; ++r) {
                    int row = drow + r;
                    if (row < n)
                        Sf[((size_t)z * 256 + row) * 3840 + c0 + f * 16 + fr] =
                            acc[f][r];
                }
        }
        grid.sync();

        // ---- phase B: cell (sum 2 K-partials) ----
        int tot = n * HD;
        for (int idx = gt; idx < tot; idx += 61440) {
            int i = idx / HD, j = idx - i * HD;
            int g = off + i;
            int id = ids[g];
            const float* s0 = Sf + (size_t)i * 3840;
            const float* s1 = Sf + (size_t)(256 + i) * 3840;
            float si = s0[j] + s1[j];
            float so = s0[768 + j] + s1[768 + j];
            float su = s0[1536 + j] + s1[1536 + j];
            float p0 = s0[2304 + j] + s1[2304 + j];
            float p1 = s0[3072 + j] + s1[3072 + j];
            const float* w = Wiou + (size_t)id * 2304;
            float iv = sigm(si + w[j] + biou[j]);
            float ov = sigm(so + w[768 + j] + biou[768 + j]);
            float gv = tanhf(su + w[1536 + j] + biou[1536 + j]);
            float xf = Wf[(size_t)id * HD + j] + bfv[j];
            float f0 = sigm(p0 + xf);
            float f1 = sigm(p1 + xf);
            float c = iv * gv
                    + f0 * b2f(c_all[(size_t)(2 * g + 1) * HD + j])
                    + f1 * b2f(c_all[(size_t)(2 * g + 2) * HD + j]);
            h_all[(size_t)g * HD + j] = f2b(ov * tanhf(c));
            c_all[(size_t)g * HD + j] = f2b(c);
        }
        if (d > 0) grid.sync();
    }
}

// ---------------------------------------------------------------------------
// 8-phase 256x256 bf16 MFMA GEMM (T2+T3+T4+T5, T1 XCD swizzle) — R16-proven.
// ---------------------------------------------------------------------------
template <int GATHER>
__global__ __launch_bounds__(512, 2) void mm8_k(
    const bf16* __restrict__ A, const bf16* __restrict__ BT,
    bf16* __restrict__ Cb, int M, int N, int K, int NBX)
{
    __shared__ short Al[2][16384];
    __shared__ short Bl[2][16384];

    const int tid  = threadIdx.x;
    const int lane = tid & 63;
    const int wid  = tid >> 6;
    const int wr = wid >> 2, wc = wid & 3;
    const int NT = K >> 6;

    int T = gridDim.x, L = blockIdx.x;
    int q = T >> 3, r = T & 7;
    int xcd = L & 7, i8 = L >> 3;
    int v = (xcd < r ? xcd * (q + 1) : r * (q + 1) + (xcd - r) * q) + i8;
    const int bx = v % NBX, by = v / NBX;

    const int srow = wid * 8 + (lane >> 3);
    const int scol = ((lane & 7) ^ (lane >> 3)) * 8;
    const int frow = lane & 15;
    const int fq   = lane >> 4;

    f32x4 acc[8][4] = {};

    auto stageA = [&](int t, int cr) {
        int slot = t & 1;
        int grow = by * 256 + cr + srow;
        if (grow > M - 1) grow = M - 1;
        int kb = t * 64;
        const bf16* src;
        if constexpr (GATHER) {
            int ch = kb / 768;
            int node = (ch == 0) ? grow : (2 * grow + ch);
            src = A + (size_t)node * 768 + (kb - ch * 768) + scol;
        } else {
            src = A + (size_t)grow * K + kb + scol;
        }
        gload16(src, &Al[slot][(cr + wid * 8) * 64]);
    };
    auto stageB = [&](int t, int cr) {
        int slot = t & 1;
        const bf16* src = BT + (size_t)(bx * 256 + cr + srow) * K + t * 64 + scol;
        gload16(src, &Bl[slot][(cr + wid * 8) * 64]);
    };

    stageB(0, 0);   stageB(0, 64);
    stageB(0, 128); stageB(0, 192);
    stageA(0, 0);   stageA(0, 128);
    stageA(0, 64);  stageA(0, 192);
    stageB(1, 0);   stageB(1, 64);
    stageB(1, 128); stageB(1, 192);
    stageA(1, 0);   stageA(1, 128);
    asm volatile("s_waitcnt vmcnt(6)" ::: "memory");
    __builtin_amdgcn_s_barrier();

#define PHASE(Q, STAGES, TAILWAIT)                                           \
    {                                                                        \
        bf16x8 a[2][2];                                                      \
        _Pragma("unroll")                                                    \
        for (int mq = 0; mq < 2; ++mq)                                       \
            _Pragma("unroll")                                                \
            for (int ks = 0; ks < 2; ++ks)                                   \
                a[mq][ks] = *(const bf16x8*)&Ax[                             \
                    (wr * 128 + ((Q) * 2 + mq) * 16 + frow) * 64             \
                    + (((ks * 4 + fq) ^ (frow & 7)) * 8)];                   \
        STAGES;                                                              \
        __builtin_amdgcn_s_barrier();                                        \
        asm volatile("s_waitcnt lgkmcnt(0)" ::: "memory");                   \
        __builtin_amdgcn_sched_barrier(0);                                   \
        __builtin_amdgcn_s_setprio(1);                                       \
        _Pragma("unroll")                                                    \
        for (int mq = 0; mq < 2; ++mq)                                       \
            _Pragma("unroll")                                                \
            for (int nf = 0; nf < 4; ++nf)                                   \
                _Pragma("unroll")                                            \
                for (int ks = 0; ks < 2; ++ks)                               \
                    acc[(Q) * 2 + mq][nf] =                                  \
                        __builtin_amdgcn_mfma_f32_16x16x32_bf16(             \
                            a[mq][ks], b[nf][ks], acc[(Q) * 2 + mq][nf], 0, 0, 0); \
        __builtin_amdgcn_s_setprio(0);                                       \
        TAILWAIT;                                                            \
        __builtin_amdgcn_s_barrier();                                        \
    }

    for (int t = 0; t < NT; ++t) {
        short* Ax = Al[t & 1];
        short* Bx = Bl[t & 1];
        bf16x8 b[4][2];
#pragma unroll
        for (int nf = 0; nf < 4; ++nf)
#pragma unroll
            for (int ks = 0; ks < 2; ++ks)
                b[nf][ks] = *(const bf16x8*)&Bx[
                    (wc * 64 + nf * 16 + frow) * 64
                    + (((ks * 4 + fq) ^ (frow & 7)) * 8)];

        PHASE(0,
              { if (t + 1 < NT) { stageA(t + 1, 64); stageA(t + 1, 192); } },
              {})
        PHASE(1,
              { if (t + 2 < NT) { stageB(t + 2, 0); stageB(t + 2, 64); } },
              {})
        PHASE(2,
              { if (t + 2 < NT) { stageB(t + 2, 128); stageB(t + 2, 192); } },
              {})
        PHASE(3,
              { if (t + 2 < NT) { stageA(t + 2, 0); stageA(t + 2, 128); } },
              {
                  if (t + 2 < NT) asm volatile("s_waitcnt vmcnt(6)" ::: "memory");
                  else            asm volatile("s_waitcnt vmcnt(0)" ::: "memory");
              })
    }
#undef PHASE

#pragma unroll
    for (int mf = 0; mf < 8; ++mf) {
#pragma unroll
        for (int r2 = 0; r2 < 4; ++r2) {
            int row = by * 256 + wr * 128 + mf * 16 + (lane >> 4) * 4 + r2;
            if (row >= M) continue;
#pragma unroll
            for (int nf = 0; nf < 4; ++nf) {
                int col = bx * 256 + wc * 64 + nf * 16 + (lane & 15);
                Cb[(size_t)row * N + col] = f2b(acc[mf][nf][r2]);
            }
        }
    }
}

// ---------------------------------------------------------------------------
// bf16 MFMA GEMM (R8-proven m97 structure) with K-split support.
// ---------------------------------------------------------------------------
template <int EPI, int GATHER>
__global__ __launch_bounds__(256) void mm_k(
    const bf16* __restrict__ A, const bf16* __restrict__ BT,
    float* __restrict__ Cf, bf16* __restrict__ Cb,
    const float* __restrict__ bias,
    int M, int N, int Kc, int Kfull)
{
    __shared__ short As[128 * 32];
    __shared__ short Bs[128 * 32];

    int tid  = threadIdx.x;
    int lane = tid & 63;
    int wave = tid >> 6;
    int wr = wave >> 1, wc = wave & 1;
    int bx = blockIdx.x, by = blockIdx.y;
    int colbase = blockIdx.z * Kc;
    if constexpr (EPI == 0) Cf += (size_t)blockIdx.z * ((size_t)M * N);

    f32x4 acc[4][4] = {};

    int sr  = lane >> 2;
    int sc8 = (lane & 3) * 8;
    int arow0 = by * 128 + wave * 16 + sr;
    int arow1 = arow0 + 64;
    if (arow0 > M - 1) arow0 = M - 1;
    if (arow1 > M - 1) arow1 = M - 1;
    const bf16* gA0 = A + (size_t)arow0 * Kfull + colbase + sc8;
    const bf16* gA1 = A + (size_t)arow1 * Kfull + colbase + sc8;
    const bf16* gB0 = BT + (size_t)(bx * 128 + wave * 16 + sr) * Kfull + colbase + sc8;
    const bf16* gB1 = BT + (size_t)(bx * 128 + wave * 16 + sr + 64) * Kfull + colbase + sc8;
    short* lA0 = As + wave * 512;
    short* lA1 = As + wave * 512 + 2048;
    short* lB0 = Bs + wave * 512;
    short* lB1 = Bs + wave * 512 + 2048;

    int fr = lane & 15;
    int fk = (lane >> 4) << 3;
    const short* pAf = As + (wr * 64 + fr) * 32 + fk;
    const short* pBf = Bs + (wc * 64 + fr) * 32 + fk;

    for (int kt = 0; kt < Kc; kt += 32) {
        if constexpr (GATHER) {
            int abs0 = colbase + kt;
            int ch = (abs0 >= 768) + (abs0 >= 1536);
            int col = abs0 - ch * 768 + sc8;
            int n0 = (ch == 0) ? arow0 : (2 * arow0 + ch);
            int n1 = (ch == 0) ? arow1 : (2 * arow1 + ch);
            gload16(A + (size_t)n0 * HD + col, lA0);
            gload16(A + (size_t)n1 * HD + col, lA1);
        } else {
            gload16(gA0 + kt, lA0);
            gload16(gA1 + kt, lA1);
        }
        gload16(gB0 + kt, lB0);
        gload16(gB1 + kt, lB1);
        __syncthreads();

        bf16x8 a[4], b[4];
#pragma unroll
        for (int m = 0; m < 4; m++) a[m] = *(const bf16x8*)(pAf + m * 512);
#pragma unroll
        for (int n = 0; n < 4; n++) b[n] = *(const bf16x8*)(pBf + n * 512);
#pragma unroll
        for (int m = 0; m < 4; m++)
#pragma unroll
            for (int n = 0; n < 4; n++)
                acc[m][n] = __builtin_amdgcn_mfma_f32_16x16x32_bf16(
                    a[m], b[n], acc[m][n], 0, 0, 0);
        __syncthreads();
    }

    int rbase = by * 128 + wr * 64 + ((lane >> 4) << 2);
    int cbase = bx * 128 + wc * 64 + fr;
#pragma unroll
    for (int m = 0; m < 4; m++) {
#pragma unroll
        for (int r = 0; r < 4; r++) {
            int row = rbase + m * 16 + r;
            if (row >= M) continue;
#pragma unroll
            for (int n = 0; n < 4; n++) {
                int col = cbase + n * 16;
                float v = acc[m][n][r];
                if constexpr (EPI == 1) {
                    v = fmaxf(v + bias[col], 0.f);
                    Cb[(size_t)row * N + col] = f2b(v);
                } else if constexpr (EPI == 3) {
                    Cb[(size_t)row * N + col] = f2b(v);
                } else {
                    Cf[(size_t)row * N + col] = v;
                }
            }
        }
    }
}

// ---------------------------------------------------------------------------
// Pass-1 cell (R8 scalar form): bf16 S(m x 3840) -> bf16 h,c.
// ---------------------------------------------------------------------------
__global__ __launch_bounds__(256) void cell1_k(
    const int* __restrict__ ids, const bf16* __restrict__ S,
    const float* __restrict__ Wiou, const float* __restrict__ biou,
    const float* __restrict__ Wf, const float* __restrict__ bfv,
    bf16* __restrict__ h_all, bf16* __restrict__ c_all,
    int m, int offAbs)
{
    int idx = blockIdx.x * blockDim.x + threadIdx.x;
    if (idx >= m * HD) return;
    int i = idx / HD, j = idx - i * HD;
    int g = offAbs + i;
    int id = ids[g];
    const bf16* s = S + (size_t)i * 3840;
    const float* w = Wiou + (size_t)id * 2304;
    float iv = sigm(b2f(s[j]) + w[j] + biou[j]);
    float ov = sigm(b2f(s[HD + j]) + w[HD + j] + biou[HD + j]);
    float gv = tanhf(b2f(s[2 * HD + j]) + w[2 * HD + j] + biou[2 * HD + j]);
    float xf = Wf[(size_t)id * HD + j] + bfv[j];
    float f0 = sigm(b2f(s[3 * HD + j]) + xf);
    float f1 = sigm(b2f(s[4 * HD + j]) + xf);
    float c = iv * gv
            + f0 * b2f(c_all[(size_t)(2 * g + 1) * HD + j])
            + f1 * b2f(c_all[(size_t)(2 * g + 2) * HD + j]);
    h_all[(size_t)g * HD + j] = f2b(ov * tanhf(c));
    c_all[(size_t)g * HD + j] = f2b(c);
}

// ---------------------------------------------------------------------------
// Pass-2 cell (R8 scalar form): bf16 S(m x 4608) -> bf16 h3.
// ---------------------------------------------------------------------------
__global__ __launch_bounds__(256) void cell2_k(
    const int* __restrict__ ids, const bf16* __restrict__ S,
    const float* __restrict__ Wiou, const float* __restrict__ biou,
    const float* __restrict__ Wf, const float* __restrict__ bfv,
    const bf16* __restrict__ c_all, bf16* __restrict__ h3_all,
    int m, int g0)
{
    int idx = blockIdx.x * blockDim.x + threadIdx.x;
    if (idx >= m * HD) return;
    int i = idx / HD, j = idx - i * HD;
    int g = g0 + i;
    int id = ids[g];
    const bf16* s = S + (size_t)i * 4608;
    const float* w = Wiou + (size_t)id * 2304;
    float iv = sigm(b2f(s[j]) + w[j] + biou[j]);
    float ov = sigm(b2f(s[HD + j]) + w[HD + j] + biou[HD + j]);
    float gv = tanhf(b2f(s[2 * HD + j]) + w[2 * HD + j] + biou[2 * HD + j]);
    float xf = Wf[(size_t)id * HD + j] + bfv[j];
    float f0 = sigm(b2f(s[3 * HD + j]) + xf);
    float f1 = sigm(b2f(s[4 * HD + j]) + xf);
    float f2 = sigm(b2f(s[5 * HD + j]) + xf);
    float c = iv * gv
            + f0 * b2f(c_all[(size_t)g * HD + j])
            + f1 * b2f(c_all[(size_t)(2 * g + 1) * HD + j])
            + f2 * b2f(c_all[(size_t)(2 * g + 2) * HD + j]);
    h3_all[(size_t)g * HD + j] = f2b(ov * tanhf(c));
}

// ---------------------------------------------------------------------------
// Head softmaxes from logits L[g][128]; bc holds fused biases. fp32 out.
// ---------------------------------------------------------------------------
__global__ __launch_bounds__(256) void hsm_k(
    const float* __restrict__ L, const int* __restrict__ mask,
    const float* __restrict__ bc, float* __restrict__ out)
{
    int g = blockIdx.x * 4 + (threadIdx.x >> 6);
    if (g >= N_NODES) return;
    int t = threadIdx.x & 63;
    const float* lr = L + (size_t)g * 128;

    bool on = mask[(size_t)g * 64 + t] > 0;
    float x = (lr[4 + t] + bc[4 + t]) * (1.0f / TEMP);
    float mx = on ? x : -INFINITY;
#pragma unroll
    for (int o = 32; o; o >>= 1) mx = fmaxf(mx, __shfl_xor(mx, o));
    float e = on ? __expf(x - mx) : 0.0f;
    float s = e;
#pragma unroll
    for (int o = 32; o; o >>= 1) s += __shfl_xor(s, o);
    float r = (s > 0.f) ? e / s : (1.0f / 64.0f);
    out[(size_t)g * 68 + 4 + t] = r;

    if (t == 0) {
        float a = (lr[0] + bc[0]) * (1.0f / TEMP);
        float b = (lr[1] + bc[1]) * (1.0f / TEMP);
        float m2 = fmaxf(a, b);
        float e0 = __expf(a - m2), e1 = __expf(b - m2);
        out[(size_t)g * 68 + 0] = e0 / (e0 + e1);
        out[(size_t)g * 68 + 1] = e1 / (e0 + e1);
    } else if (t == 1) {
        float a = (lr[2] + bc[2]) * (1.0f / TEMP);
        float b = (lr[3] + bc[3]) * (1.0f / TEMP);
        float m2 = fmaxf(a, b);
        float e0 = __expf(a - m2), e1 = __expf(b - m2);
        out[(size_t)g * 68 + 2] = e0 / (e0 + e1);
        out[(size_t)g * 68 + 3] = e1 / (e0 + e1);
    }
}

// ---------------------------------------------------------------------------
extern "C" void kernel_launch(void* const* d_in, const int* in_sizes, int n_in,
                              void* d_out, int out_size, void* d_ws, size_t ws_size,
                              hipStream_t stream)
{
    const int*   ids     = (const int*)d_in[0];
    const int*   mask    = (const int*)d_in[1];
    const float* Wb_iou  = (const float*)d_in[2];
    const float* Ub_iou  = (const float*)d_in[3];
    const float* bb_iou  = (const float*)d_in[4];
    const float* Wb_f    = (const float*)d_in[5];
    const float* Ub_f    = (const float*)d_in[6];
    const float* bb_f    = (const float*)d_in[7];
    const float* Wt_iou  = (const float*)d_in[8];
    const float* Ut_iou  = (const float*)d_in[9];
    const float* bt_iou  = (const float*)d_in[10];
    const float* Wt_f    = (const float*)d_in[11];
    const float* Ut_f    = (const float*)d_in[12];
    const float* bt_f    = (const float*)d_in[13];
    const float* ffn_W1  = (const float*)d_in[14];
    const float* ffn_b1  = (const float*)d_in[15];
    const float* ffn_W2  = (const float*)d_in[16];
    const float* ffn_b2  = (const float*)d_in[17];
    const float* hl_W    = (const float*)d_in[18];
    const float* hl_b    = (const float*)d_in[19];
    const float* int_W   = (const float*)d_in[20];
    const float* int_b   = (const float*)d_in[21];
    const float* act_W   = (const float*)d_in[22];
    const float* act_b   = (const float*)d_in[23];

    // ---- workspace layout ----
    char* p = (char*)d_ws;
    bf16* h_all  = (bf16*)p; p += (size_t)NHF * 2;
    bf16* c_all  = (bf16*)p; p += (size_t)NHF * 2;
    bf16* h3_all = (bf16*)p; p += (size_t)NHF * 2;
    bf16* BT1 = (bf16*)p; p += (size_t)T1SZ * 2;
    bf16* BT2 = (bf16*)p; p += (size_t)T2SZ * 2;
    bf16* W1T = (bf16*)p; p += (size_t)WSZ * 2;
    bf16* WcT = (bf16*)p; p += (size_t)128 * 768 * 2;
    bf16* WhT = (bf16*)p; p += (size_t)HSZ2 * 2;
    bf16* W2b = (bf16*)p; p += (size_t)WSZ * 2;
    bf16* Vh  = (bf16*)p; p += (size_t)512 * HD * 2;
    bf16* Vc  = (bf16*)p; p += (size_t)512 * HD * 2;
    bf16* Vh3 = (bf16*)p; p += (size_t)512 * HD * 2;
    float* bc = (float*)p; p += 512;
    bf16* Sb  = (bf16*)p;              // bf16 S: up to 8191 x 4608 = 75.5 MB
    float* Sf = (float*)Sb;            // fp32 tail partials [2][256][3840]
    bf16* t1  = c_all;                 // FFN hidden aliases dead c
    float* Lg = (float*)h3_all;        // head logits alias h3 (dead after FFN1)

    // ---- weight conversions (coalesced) ----
    tconv_k<<<16704, 256, 0, stream>>>(
        Ub_iou, Ub_f, Ut_iou, Ut_f, ffn_W1, BT1, BT2, W1T);
    misc_k<<<(HSZ2 + WSZ + 255) / 256, 256, 0, stream>>>(
        hl_W, int_W, act_W, ffn_W2, WhT, W2b);
    bck_k<<<1, 128, 0, stream>>>(
        ffn_b2, hl_W, hl_b, int_W, int_b, act_W, act_b, bc);
    mm_k<3, 0><<<dim3(6, 1), 256, 0, stream>>>(
        WhT, W2b, nullptr, WcT, nullptr, 128, 768, 768, 768);

    // ---- leaves: vocab precompute + scatter ----
    vocab_k<<<(512 * HD + 255) / 256, 256, 0, stream>>>(
        Wb_iou, bb_iou, Wt_iou, bt_iou, Vh, Vc, Vh3);
    lscat_k<<<(8192 * 96 + 255) / 256, 256, 0, stream>>>(
        ids, Vh, Vc, Vh3, h_all, c_all, h3_all);

    // ---- pass 1 big/mid levels (d=12..9) ----
    for (int d = 12; d >= 9; --d) {
        int n = 1 << d;
        int childoff = 2 * n - 1;
        if (n >= 2048) {
            mm8_k<0><<<15 * (n / 256), 512, 0, stream>>>(
                h_all + (size_t)childoff * HD, BT1, Sb, n, 3840, 1536, 15);
        } else {
            mm_k<3, 0><<<dim3(30, n / 128), 256, 0, stream>>>(
                h_all + (size_t)childoff * HD, BT1, nullptr, Sb, nullptr,
                n, 3840, 1536, 1536);
        }
        cell1_k<<<(n * HD + 255) / 256, 256, 0, stream>>>(
            ids, Sb, Wb_iou, bb_iou, Wb_f, bb_f, h_all, c_all, n, n - 1);
    }

    // ---- pass 1 tail (d=8..0): ONE cooperative kernel ----
    {
        void* args[] = {
            (void*)&ids, (void*)&h_all, (void*)&c_all, (void*)&BT1,
            (void*)&Wb_iou, (void*)&bb_iou, (void*)&Wb_f, (void*)&bb_f,
            (void*)&Sf
        };
        hipLaunchCooperativeKernel((void*)tail_k, dim3(120), dim3(512),
                                   args, 0, stream);
    }

    // ---- pass 2: 8-phase (XCD-swizzled), gather fused into GEMM ----
    mm8_k<1><<<18 * 32, 512, 0, stream>>>(
        h_all, BT2, Sb, NLEAF_OFF, 4608, 2304, 18);
    cell2_k<<<(NLEAF_OFF * HD + 255) / 256, 256, 0, stream>>>(
        ids, Sb, Wt_iou, bt_iou, Wt_f, bt_f, c_all, h3_all, NLEAF_OFF, 0);

    // ---- FFN1 (relu epilogue) ----
    mm_k<1, 0><<<dim3(6, 128), 256, 0, stream>>>(
        h3_all, W1T, nullptr, t1, ffn_b1, N_NODES, 768, 768, 768);

    // ---- heads: folded logits GEMM + softmax ----
    mm_k<0, 0><<<dim3(1, 128), 256, 0, stream>>>(
        t1, WcT, Lg, nullptr, nullptr, N_NODES, 128, 768, 768);
    hsm_k<<<(N_NODES + 3) / 4, 256, 0, stream>>>(
        Lg, mask, bc, (float*)d_out);
}

// Round 18
// 783.953 us; speedup vs baseline: 1.5064x; 1.5064x over previous
//
#include <hip/hip_runtime.h>
#include <hip/hip_bf16.h>

#define HD 768
#define N_NODES 16383
#define NLEAF_OFF 8191     // first leaf node index (level d=13 offset)
#define NHF 12582144       // N_NODES * HD
#define TEMP 3.0f

using bf16 = __hip_bfloat16;
typedef __attribute__((ext_vector_type(8))) short bf16x8;
typedef __attribute__((ext_vector_type(4))) float f32x4;

__device__ __forceinline__ float sigm(float x) { return 1.0f / (1.0f + __expf(-x)); }
__device__ __forceinline__ float b2f(bf16 v)   { return __bfloat162float(v); }
__device__ __forceinline__ bf16  f2b(float v)  { return __float2bfloat16(v); }

// async global->LDS, 16B per lane. LDS dest = wave-uniform base + lane*16.
__device__ __forceinline__ void gload16(const void* g, void* l) {
    __builtin_amdgcn_global_load_lds(
        (const __attribute__((address_space(1))) unsigned int*)g,
        (__attribute__((address_space(3))) unsigned int*)l, 16, 0, 0);
}

#define T1SZ 5898240      // 3840*1536
#define T2SZ 10616832     // 4608*2304
#define WSZ  589824       // 768*768

// ---------------------------------------------------------------------------
// Tiled transpose-convert (R11-proven): BT1, BT2, W1T, coalesced both sides.
// ---------------------------------------------------------------------------
__global__ __launch_bounds__(256) void tconv_k(
    const float* __restrict__ Ub_iou, const float* __restrict__ Ub_f,
    const float* __restrict__ Ut_iou, const float* __restrict__ Ut_f,
    const float* __restrict__ ffn_W1,
    bf16* __restrict__ BT1, bf16* __restrict__ BT2, bf16* __restrict__ W1T)
{
    int t = blockIdx.x;
    const float* src; bf16* dst; int C, S, kt, nt;
    if (t < 3456) {
        src = Ub_iou; dst = BT1; C = 2304; S = 1536;
        kt = t % 48; nt = t / 48;
    } else if (t < 5760) {
        int u = t - 3456; int piece = u / 576; u -= piece * 576;
        int kk = piece >> 1, l = piece & 1;
        src = Ub_f + (size_t)(kk * 2 + l) * WSZ;
        dst = BT1 + (size_t)(2304 + kk * 768) * 1536 + l * 768;
        C = 768; S = 1536; kt = u % 24; nt = u / 24;
    } else if (t < 10944) {
        int u = t - 5760;
        src = Ut_iou; dst = BT2; C = 2304; S = 2304;
        kt = u % 72; nt = u / 72;
    } else if (t < 16128) {
        int u = t - 10944; int piece = u / 576; u -= piece * 576;
        int kk = piece / 3, l = piece - kk * 3;
        src = Ut_f + (size_t)(kk * 3 + l) * WSZ;
        dst = BT2 + (size_t)(2304 + kk * 768) * 2304 + l * 768;
        C = 768; S = 2304; kt = u % 24; nt = u / 24;
    } else {
        int u = t - 16128;
        src = ffn_W1; dst = W1T; C = 768; S = 768;
        kt = u % 24; nt = u / 24;
    }
    int k0 = kt * 32, n0 = nt * 32;

    __shared__ float tl[32][33];
    int rr = threadIdx.x >> 5, c = threadIdx.x & 31;
#pragma unroll
    for (int r = 0; r < 32; r += 8)
        tl[rr + r][c] = src[(size_t)(k0 + rr + r) * C + n0 + c];
    __syncthreads();
#pragma unroll
    for (int r = 0; r < 32; r += 8)
        dst[(size_t)(n0 + rr + r) * S + k0 + c] = f2b(tl[c][rr + r]);
}

// ---------------------------------------------------------------------------
// Misc converts: WhT[128][768] + W2 bf16 cast.
// ---------------------------------------------------------------------------
#define HSZ2 98304        // 128*768
__global__ __launch_bounds__(256) void misc_k(
    const float* __restrict__ hlW, const float* __restrict__ intW,
    const float* __restrict__ actW, const float* __restrict__ W2,
    bf16* __restrict__ WhT, bf16* __restrict__ W2b)
{
    int idx = blockIdx.x * 256 + threadIdx.x;
    if (idx < HSZ2) {
        int n = idx / 768, j = idx - n * 768;
        float v = 0.f;
        if (n < 2)       v = hlW[(size_t)j * 2 + n];
        else if (n < 4)  v = intW[(size_t)j * 2 + (n - 2)];
        else if (n < 68) v = actW[(size_t)j * 64 + (n - 4)];
        WhT[idx] = f2b(v);
    } else if (idx < HSZ2 + WSZ) {
        int i2 = idx - HSZ2;
        W2b[i2] = f2b(W2[i2]);
    }
}

// Fused bias: bc[n] = sum_j b2[j]*Wh[j][n] + head_bias(n).
__global__ __launch_bounds__(128) void bck_k(
    const float* __restrict__ b2,
    const float* __restrict__ hlW, const float* __restrict__ hlb,
    const float* __restrict__ intW, const float* __restrict__ intb,
    const float* __restrict__ actW, const float* __restrict__ actb,
    float* __restrict__ bc)
{
    int n = threadIdx.x;
    float s = 0.f;
    for (int j = 0; j < 768; ++j) {
        float wh = 0.f;
        if (n < 2)       wh = hlW[(size_t)j * 2 + n];
        else if (n < 4)  wh = intW[(size_t)j * 2 + (n - 2)];
        else if (n < 68) wh = actW[(size_t)j * 64 + (n - 4)];
        s = fmaf(b2[j], wh, s);
    }
    float hb = 0.f;
    if (n < 2)       hb = hlb[n];
    else if (n < 4)  hb = intb[n - 2];
    else if (n < 68) hb = actb[n - 4];
    bc[n] = s + hb;
}

// ---------------------------------------------------------------------------
// Vocab precompute + leaf scatter (R16-proven).
// ---------------------------------------------------------------------------
__global__ __launch_bounds__(256) void vocab_k(
    const float* __restrict__ Wb, const float* __restrict__ bb,
    const float* __restrict__ Wt, const float* __restrict__ bt,
    bf16* __restrict__ Vh, bf16* __restrict__ Vc, bf16* __restrict__ Vh3)
{
    int idx = blockIdx.x * 256 + threadIdx.x;
    if (idx >= 512 * HD) return;
    int id = idx / HD, j = idx - id * HD;
    const float* w = Wb + (size_t)id * 3 * HD;
    float iv = sigm(w[j] + bb[j]);
    float ov = sigm(w[HD + j] + bb[HD + j]);
    float gv = tanhf(w[2 * HD + j] + bb[2 * HD + j]);
    float c = iv * gv;
    Vh[idx] = f2b(ov * tanhf(c));
    Vc[idx] = f2b(c);

    const float* w2 = Wt + (size_t)id * 3 * HD;
    float iv2 = sigm(w2[j] + bt[j]);
    float ov2 = sigm(w2[HD + j] + bt[HD + j]);
    float gv2 = tanhf(w2[2 * HD + j] + bt[2 * HD + j]);
    float c2 = iv2 * gv2;
    Vh3[idx] = f2b(ov2 * tanhf(c2));
}

__global__ __launch_bounds__(256) void lscat_k(
    const int* __restrict__ ids,
    const bf16* __restrict__ Vh, const bf16* __restrict__ Vc,
    const bf16* __restrict__ Vh3,
    bf16* __restrict__ h_all, bf16* __restrict__ c_all, bf16* __restrict__ h3_all)
{
    int idx = blockIdx.x * 256 + threadIdx.x;
    if (idx >= 8192 * 96) return;
    int i = idx / 96, j8 = (idx - i * 96) * 8;
    int g = NLEAF_OFF + i;
    size_t so = (size_t)ids[g] * HD + j8;
    size_t dof = (size_t)g * HD + j8;
    *(uint4*)(h_all + dof)  = *(const uint4*)(Vh + so);
    *(uint4*)(c_all + dof)  = *(const uint4*)(Vc + so);
    *(uint4*)(h3_all + dof) = *(const uint4*)(Vh3 + so);
}

// ---------------------------------------------------------------------------
// 8-phase 256x256 bf16 MFMA GEMM (T2+T3+T4+T5, T1 XCD swizzle) — R16-proven.
// EPI 0: plain bf16 store. EPI 1: bias+relu -> bf16 (FFN1).
// ---------------------------------------------------------------------------
template <int GATHER, int EPI>
__global__ __launch_bounds__(512, 2) void mm8_k(
    const bf16* __restrict__ A, const bf16* __restrict__ BT,
    bf16* __restrict__ Cb, const float* __restrict__ bias,
    int M, int N, int K, int NBX)
{
    __shared__ short Al[2][16384];
    __shared__ short Bl[2][16384];

    const int tid  = threadIdx.x;
    const int lane = tid & 63;
    const int wid  = tid >> 6;
    const int wr = wid >> 2, wc = wid & 3;
    const int NT = K >> 6;

    int T = gridDim.x, L = blockIdx.x;
    int q = T >> 3, r = T & 7;
    int xcd = L & 7, i8 = L >> 3;
    int v = (xcd < r ? xcd * (q + 1) : r * (q + 1) + (xcd - r) * q) + i8;
    const int bx = v % NBX, by = v / NBX;

    const int srow = wid * 8 + (lane >> 3);
    const int scol = ((lane & 7) ^ (lane >> 3)) * 8;
    const int frow = lane & 15;
    const int fq   = lane >> 4;

    f32x4 acc[8][4] = {};

    auto stageA = [&](int t, int cr) {
        int slot = t & 1;
        int grow = by * 256 + cr + srow;
        if (grow > M - 1) grow = M - 1;
        int kb = t * 64;
        const bf16* src;
        if constexpr (GATHER) {
            int ch = kb / 768;
            int node = (ch == 0) ? grow : (2 * grow + ch);
            src = A + (size_t)node * 768 + (kb - ch * 768) + scol;
        } else {
            src = A + (size_t)grow * K + kb + scol;
        }
        gload16(src, &Al[slot][(cr + wid * 8) * 64]);
    };
    auto stageB = [&](int t, int cr) {
        int slot = t & 1;
        const bf16* src = BT + (size_t)(bx * 256 + cr + srow) * K + t * 64 + scol;
        gload16(src, &Bl[slot][(cr + wid * 8) * 64]);
    };

    stageB(0, 0);   stageB(0, 64);
    stageB(0, 128); stageB(0, 192);
    stageA(0, 0);   stageA(0, 128);
    stageA(0, 64);  stageA(0, 192);
    stageB(1, 0);   stageB(1, 64);
    stageB(1, 128); stageB(1, 192);
    stageA(1, 0);   stageA(1, 128);
    asm volatile("s_waitcnt vmcnt(6)" ::: "memory");
    __builtin_amdgcn_s_barrier();

#define PHASE(Q, STAGES, TAILWAIT)                                           \
    {                                                                        \
        bf16x8 a[2][2];                                                      \
        _Pragma("unroll")                                                    \
        for (int mq = 0; mq < 2; ++mq)                                       \
            _Pragma("unroll")                                                \
            for (int ks = 0; ks < 2; ++ks)                                   \
                a[mq][ks] = *(const bf16x8*)&Ax[                             \
                    (wr * 128 + ((Q) * 2 + mq) * 16 + frow) * 64             \
                    + (((ks * 4 + fq) ^ (frow & 7)) * 8)];                   \
        STAGES;                                                              \
        __builtin_amdgcn_s_barrier();                                        \
        asm volatile("s_waitcnt lgkmcnt(0)" ::: "memory");                   \
        __builtin_amdgcn_sched_barrier(0);                                   \
        __builtin_amdgcn_s_setprio(1);                                       \
        _Pragma("unroll")                                                    \
        for (int mq = 0; mq < 2; ++mq)                                       \
            _Pragma("unroll")                                                \
            for (int nf = 0; nf < 4; ++nf)                                   \
                _Pragma("unroll")                                            \
                for (int ks = 0; ks < 2; ++ks)                               \
                    acc[(Q) * 2 + mq][nf] =                                  \
                        __builtin_amdgcn_mfma_f32_16x16x32_bf16(             \
                            a[mq][ks], b[nf][ks], acc[(Q) * 2 + mq][nf], 0, 0, 0); \
        __builtin_amdgcn_s_setprio(0);                                       \
        TAILWAIT;                                                            \
        __builtin_amdgcn_s_barrier();                                        \
    }

    for (int t = 0; t < NT; ++t) {
        short* Ax = Al[t & 1];
        short* Bx = Bl[t & 1];
        bf16x8 b[4][2];
#pragma unroll
        for (int nf = 0; nf < 4; ++nf)
#pragma unroll
            for (int ks = 0; ks < 2; ++ks)
                b[nf][ks] = *(const bf16x8*)&Bx[
                    (wc * 64 + nf * 16 + frow) * 64
                    + (((ks * 4 + fq) ^ (frow & 7)) * 8)];

        PHASE(0,
              { if (t + 1 < NT) { stageA(t + 1, 64); stageA(t + 1, 192); } },
              {})
        PHASE(1,
              { if (t + 2 < NT) { stageB(t + 2, 0); stageB(t + 2, 64); } },
              {})
        PHASE(2,
              { if (t + 2 < NT) { stageB(t + 2, 128); stageB(t + 2, 192); } },
              {})
        PHASE(3,
              { if (t + 2 < NT) { stageA(t + 2, 0); stageA(t + 2, 128); } },
              {
                  if (t + 2 < NT) asm volatile("s_waitcnt vmcnt(6)" ::: "memory");
                  else            asm volatile("s_waitcnt vmcnt(0)" ::: "memory");
              })
    }
#undef PHASE

#pragma unroll
    for (int mf = 0; mf < 8; ++mf) {
#pragma unroll
        for (int r2 = 0; r2 < 4; ++r2) {
            int row = by * 256 + wr * 128 + mf * 16 + (lane >> 4) * 4 + r2;
            if (row >= M) continue;
#pragma unroll
            for (int nf = 0; nf < 4; ++nf) {
                int col = bx * 256 + wc * 64 + nf * 16 + (lane & 15);
                float vv = acc[mf][nf][r2];
                if constexpr (EPI == 1) vv = fmaxf(vv + bias[col], 0.f);
                Cb[(size_t)row * N + col] = f2b(vv);
            }
        }
    }
}

// ---------------------------------------------------------------------------
// bf16 MFMA GEMM (R8-proven m97 structure) with K-split support.
// ---------------------------------------------------------------------------
template <int EPI, int GATHER>
__global__ __launch_bounds__(256) void mm_k(
    const bf16* __restrict__ A, const bf16* __restrict__ BT,
    float* __restrict__ Cf, bf16* __restrict__ Cb,
    const float* __restrict__ bias,
    int M, int N, int Kc, int Kfull)
{
    __shared__ short As[128 * 32];
    __shared__ short Bs[128 * 32];

    int tid  = threadIdx.x;
    int lane = tid & 63;
    int wave = tid >> 6;
    int wr = wave >> 1, wc = wave & 1;
    int bx = blockIdx.x, by = blockIdx.y;
    int colbase = blockIdx.z * Kc;
    if constexpr (EPI == 0) Cf += (size_t)blockIdx.z * ((size_t)M * N);

    f32x4 acc[4][4] = {};

    int sr  = lane >> 2;
    int sc8 = (lane & 3) * 8;
    int arow0 = by * 128 + wave * 16 + sr;
    int arow1 = arow0 + 64;
    if (arow0 > M - 1) arow0 = M - 1;
    if (arow1 > M - 1) arow1 = M - 1;
    const bf16* gA0 = A + (size_t)arow0 * Kfull + colbase + sc8;
    const bf16* gA1 = A + (size_t)arow1 * Kfull + colbase + sc8;
    const bf16* gB0 = BT + (size_t)(bx * 128 + wave * 16 + sr) * Kfull + colbase + sc8;
    const bf16* gB1 = BT + (size_t)(bx * 128 + wave * 16 + sr + 64) * Kfull + colbase + sc8;
    short* lA0 = As + wave * 512;
    short* lA1 = As + wave * 512 + 2048;
    short* lB0 = Bs + wave * 512;
    short* lB1 = Bs + wave * 512 + 2048;

    int fr = lane & 15;
    int fk = (lane >> 4) << 3;
    const short* pAf = As + (wr * 64 + fr) * 32 + fk;
    const short* pBf = Bs + (wc * 64 + fr) * 32 + fk;

    for (int kt = 0; kt < Kc; kt += 32) {
        if constexpr (GATHER) {
            int abs0 = colbase + kt;
            int ch = (abs0 >= 768) + (abs0 >= 1536);
            int col = abs0 - ch * 768 + sc8;
            int n0 = (ch == 0) ? arow0 : (2 * arow0 + ch);
            int n1 = (ch == 0) ? arow1 : (2 * arow1 + ch);
            gload16(A + (size_t)n0 * HD + col, lA0);
            gload16(A + (size_t)n1 * HD + col, lA1);
        } else {
            gload16(gA0 + kt, lA0);
            gload16(gA1 + kt, lA1);
        }
        gload16(gB0 + kt, lB0);
        gload16(gB1 + kt, lB1);
        __syncthreads();

        bf16x8 a[4], b[4];
#pragma unroll
        for (int m = 0; m < 4; m++) a[m] = *(const bf16x8*)(pAf + m * 512);
#pragma unroll
        for (int n = 0; n < 4; n++) b[n] = *(const bf16x8*)(pBf + n * 512);
#pragma unroll
        for (int m = 0; m < 4; m++)
#pragma unroll
            for (int n = 0; n < 4; n++)
                acc[m][n] = __builtin_amdgcn_mfma_f32_16x16x32_bf16(
                    a[m], b[n], acc[m][n], 0, 0, 0);
        __syncthreads();
    }

    int rbase = by * 128 + wr * 64 + ((lane >> 4) << 2);
    int cbase = bx * 128 + wc * 64 + fr;
#pragma unroll
    for (int m = 0; m < 4; m++) {
#pragma unroll
        for (int r = 0; r < 4; r++) {
            int row = rbase + m * 16 + r;
            if (row >= M) continue;
#pragma unroll
            for (int n = 0; n < 4; n++) {
                int col = cbase + n * 16;
                float v = acc[m][n][r];
                if constexpr (EPI == 1) {
                    v = fmaxf(v + bias[col], 0.f);
                    Cb[(size_t)row * N + col] = f2b(v);
                } else if constexpr (EPI == 3) {
                    Cb[(size_t)row * N + col] = f2b(v);
                } else {
                    Cf[(size_t)row * N + col] = v;
                }
            }
        }
    }
}

// ---------------------------------------------------------------------------
// Pass-1 cell (R8 scalar form): bf16 S(m x 3840) -> bf16 h,c.
// ---------------------------------------------------------------------------
__global__ __launch_bounds__(256) void cell1_k(
    const int* __restrict__ ids, const bf16* __restrict__ S,
    const float* __restrict__ Wiou, const float* __restrict__ biou,
    const float* __restrict__ Wf, const float* __restrict__ bfv,
    bf16* __restrict__ h_all, bf16* __restrict__ c_all,
    int m, int offAbs)
{
    int idx = blockIdx.x * blockDim.x + threadIdx.x;
    if (idx >= m * HD) return;
    int i = idx / HD, j = idx - i * HD;
    int g = offAbs + i;
    int id = ids[g];
    const bf16* s = S + (size_t)i * 3840;
    const float* w = Wiou + (size_t)id * 2304;
    float iv = sigm(b2f(s[j]) + w[j] + biou[j]);
    float ov = sigm(b2f(s[HD + j]) + w[HD + j] + biou[HD + j]);
    float gv = tanhf(b2f(s[2 * HD + j]) + w[2 * HD + j] + biou[2 * HD + j]);
    float xf = Wf[(size_t)id * HD + j] + bfv[j];
    float f0 = sigm(b2f(s[3 * HD + j]) + xf);
    float f1 = sigm(b2f(s[4 * HD + j]) + xf);
    float c = iv * gv
            + f0 * b2f(c_all[(size_t)(2 * g + 1) * HD + j])
            + f1 * b2f(c_all[(size_t)(2 * g + 2) * HD + j]);
    h_all[(size_t)g * HD + j] = f2b(ov * tanhf(c));
    c_all[(size_t)g * HD + j] = f2b(c);
}

// ---------------------------------------------------------------------------
// Pass-1 cell, split-K variant: sums KS fp32 partials Sf[z][m][3840].
// ---------------------------------------------------------------------------
__global__ __launch_bounds__(256) void cell1s_k(
    const int* __restrict__ ids, const float* __restrict__ Sf,
    const float* __restrict__ Wiou, const float* __restrict__ biou,
    const float* __restrict__ Wf, const float* __restrict__ bfv,
    bf16* __restrict__ h_all, bf16* __restrict__ c_all,
    int m, int offAbs, int KS)
{
    int idx = blockIdx.x * blockDim.x + threadIdx.x;
    if (idx >= m * HD) return;
    int i = idx / HD, j = idx - i * HD;
    int g = offAbs + i;
    int id = ids[g];
    const float* s = Sf + (size_t)i * 3840;
    size_t zs = (size_t)m * 3840;
    float si = 0.f, so = 0.f, su = 0.f, p0 = 0.f, p1 = 0.f;
    for (int z = 0; z < KS; ++z) {
        const float* sz = s + z * zs;
        si += sz[j];
        so += sz[HD + j];
        su += sz[2 * HD + j];
        p0 += sz[3 * HD + j];
        p1 += sz[4 * HD + j];
    }
    const float* w = Wiou + (size_t)id * 2304;
    float iv = sigm(si + w[j] + biou[j]);
    float ov = sigm(so + w[HD + j] + biou[HD + j]);
    float gv = tanhf(su + w[2 * HD + j] + biou[2 * HD + j]);
    float xf = Wf[(size_t)id * HD + j] + bfv[j];
    float f0 = sigm(p0 + xf);
    float f1 = sigm(p1 + xf);
    float c = iv * gv
            + f0 * b2f(c_all[(size_t)(2 * g + 1) * HD + j])
            + f1 * b2f(c_all[(size_t)(2 * g + 2) * HD + j]);
    h_all[(size_t)g * HD + j] = f2b(ov * tanhf(c));
    c_all[(size_t)g * HD + j] = f2b(c);
}

// ---------------------------------------------------------------------------
// Pass-2 cell (R8 scalar form): bf16 S(m x 4608) -> bf16 h3.
// ---------------------------------------------------------------------------
__global__ __launch_bounds__(256) void cell2_k(
    const int* __restrict__ ids, const bf16* __restrict__ S,
    const float* __restrict__ Wiou, const float* __restrict__ biou,
    const float* __restrict__ Wf, const float* __restrict__ bfv,
    const bf16* __restrict__ c_all, bf16* __restrict__ h3_all,
    int m, int g0)
{
    int idx = blockIdx.x * blockDim.x + threadIdx.x;
    if (idx >= m * HD) return;
    int i = idx / HD, j = idx - i * HD;
    int g = g0 + i;
    int id = ids[g];
    const bf16* s = S + (size_t)i * 4608;
    const float* w = Wiou + (size_t)id * 2304;
    float iv = sigm(b2f(s[j]) + w[j] + biou[j]);
    float ov = sigm(b2f(s[HD + j]) + w[HD + j] + biou[HD + j]);
    float gv = tanhf(b2f(s[2 * HD + j]) + w[2 * HD + j] + biou[2 * HD + j]);
    float xf = Wf[(size_t)id * HD + j] + bfv[j];
    float f0 = sigm(b2f(s[3 * HD + j]) + xf);
    float f1 = sigm(b2f(s[4 * HD + j]) + xf);
    float f2 = sigm(b2f(s[5 * HD + j]) + xf);
    float c = iv * gv
            + f0 * b2f(c_all[(size_t)g * HD + j])
            + f1 * b2f(c_all[(size_t)(2 * g + 1) * HD + j])
            + f2 * b2f(c_all[(size_t)(2 * g + 2) * HD + j]);
    h3_all[(size_t)g * HD + j] = f2b(ov * tanhf(c));
}

// ---------------------------------------------------------------------------
// Head softmaxes from logits L[g][128]; bc holds fused biases. fp32 out.
// ---------------------------------------------------------------------------
__global__ __launch_bounds__(256) void hsm_k(
    const float* __restrict__ L, const int* __restrict__ mask,
    const float* __restrict__ bc, float* __restrict__ out)
{
    int g = blockIdx.x * 4 + (threadIdx.x >> 6);
    if (g >= N_NODES) return;
    int t = threadIdx.x & 63;
    const float* lr = L + (size_t)g * 128;

    bool on = mask[(size_t)g * 64 + t] > 0;
    float x = (lr[4 + t] + bc[4 + t]) * (1.0f / TEMP);
    float mx = on ? x : -INFINITY;
#pragma unroll
    for (int o = 32; o; o >>= 1) mx = fmaxf(mx, __shfl_xor(mx, o));
    float e = on ? __expf(x - mx) : 0.0f;
    float s = e;
#pragma unroll
    for (int o = 32; o; o >>= 1) s += __shfl_xor(s, o);
    float r = (s > 0.f) ? e / s : (1.0f / 64.0f);
    out[(size_t)g * 68 + 4 + t] = r;

    if (t == 0) {
        float a = (lr[0] + bc[0]) * (1.0f / TEMP);
        float b = (lr[1] + bc[1]) * (1.0f / TEMP);
        float m2 = fmaxf(a, b);
        float e0 = __expf(a - m2), e1 = __expf(b - m2);
        out[(size_t)g * 68 + 0] = e0 / (e0 + e1);
        out[(size_t)g * 68 + 1] = e1 / (e0 + e1);
    } else if (t == 1) {
        float a = (lr[2] + bc[2]) * (1.0f / TEMP);
        float b = (lr[3] + bc[3]) * (1.0f / TEMP);
        float m2 = fmaxf(a, b);
        float e0 = __expf(a - m2), e1 = __expf(b - m2);
        out[(size_t)g * 68 + 2] = e0 / (e0 + e1);
        out[(size_t)g * 68 + 3] = e1 / (e0 + e1);
    }
}

// ---------------------------------------------------------------------------
extern "C" void kernel_launch(void* const* d_in, const int* in_sizes, int n_in,
                              void* d_out, int out_size, void* d_ws, size_t ws_size,
                              hipStream_t stream)
{
    const int*   ids     = (const int*)d_in[0];
    const int*   mask    = (const int*)d_in[1];
    const float* Wb_iou  = (const float*)d_in[2];
    const float* Ub_iou  = (const float*)d_in[3];
    const float* bb_iou  = (const float*)d_in[4];
    const float* Wb_f    = (const float*)d_in[5];
    const float* Ub_f    = (const float*)d_in[6];
    const float* bb_f    = (const float*)d_in[7];
    const float* Wt_iou  = (const float*)d_in[8];
    const float* Ut_iou  = (const float*)d_in[9];
    const float* bt_iou  = (const float*)d_in[10];
    const float* Wt_f    = (const float*)d_in[11];
    const float* Ut_f    = (const float*)d_in[12];
    const float* bt_f    = (const float*)d_in[13];
    const float* ffn_W1  = (const float*)d_in[14];
    const float* ffn_b1  = (const float*)d_in[15];
    const float* ffn_W2  = (const float*)d_in[16];
    const float* ffn_b2  = (const float*)d_in[17];
    const float* hl_W    = (const float*)d_in[18];
    const float* hl_b    = (const float*)d_in[19];
    const float* int_W   = (const float*)d_in[20];
    const float* int_b   = (const float*)d_in[21];
    const float* act_W   = (const float*)d_in[22];
    const float* act_b   = (const float*)d_in[23];

    // ---- workspace layout ----
    char* p = (char*)d_ws;
    bf16* h_all  = (bf16*)p; p += (size_t)NHF * 2;
    bf16* c_all  = (bf16*)p; p += (size_t)NHF * 2;
    bf16* h3_all = (bf16*)p; p += (size_t)NHF * 2;
    bf16* BT1 = (bf16*)p; p += (size_t)T1SZ * 2;
    bf16* BT2 = (bf16*)p; p += (size_t)T2SZ * 2;
    bf16* W1T = (bf16*)p; p += (size_t)WSZ * 2;
    bf16* WcT = (bf16*)p; p += (size_t)128 * 768 * 2;
    bf16* WhT = (bf16*)p; p += (size_t)HSZ2 * 2;
    bf16* W2b = (bf16*)p; p += (size_t)WSZ * 2;
    bf16* Vh  = (bf16*)p; p += (size_t)512 * HD * 2;
    bf16* Vc  = (bf16*)p; p += (size_t)512 * HD * 2;
    bf16* Vh3 = (bf16*)p; p += (size_t)512 * HD * 2;
    float* bc = (float*)p; p += 512;
    bf16* Sb  = (bf16*)p;              // bf16 S: up to 8191 x 4608 = 75.5 MB
    float* Sf = (float*)Sb;            // fp32 split-K partials (tail levels)
    bf16* t1  = c_all;                 // FFN hidden aliases dead c
    float* Lg = (float*)h3_all;        // head logits alias h3 (dead after FFN1)

    // ---- weight conversions (coalesced) ----
    tconv_k<<<16704, 256, 0, stream>>>(
        Ub_iou, Ub_f, Ut_iou, Ut_f, ffn_W1, BT1, BT2, W1T);
    misc_k<<<(HSZ2 + WSZ + 255) / 256, 256, 0, stream>>>(
        hl_W, int_W, act_W, ffn_W2, WhT, W2b);
    bck_k<<<1, 128, 0, stream>>>(
        ffn_b2, hl_W, hl_b, int_W, int_b, act_W, act_b, bc);
    mm_k<3, 0><<<dim3(6, 1), 256, 0, stream>>>(
        WhT, W2b, nullptr, WcT, nullptr, 128, 768, 768, 768);

    // ---- leaves: vocab precompute + scatter ----
    vocab_k<<<(512 * HD + 255) / 256, 256, 0, stream>>>(
        Wb_iou, bb_iou, Wt_iou, bt_iou, Vh, Vc, Vh3);
    lscat_k<<<(8192 * 96 + 255) / 256, 256, 0, stream>>>(
        ids, Vh, Vc, Vh3, h_all, c_all, h3_all);

    // ---- pass 1: 8-phase for n>=2048, m97 for 512-1024, split-K tail ----
    for (int d = 12; d >= 0; --d) {
        int n = 1 << d;
        int childoff = 2 * n - 1;
        if (n >= 2048) {
            mm8_k<0, 0><<<15 * (n / 256), 512, 0, stream>>>(
                h_all + (size_t)childoff * HD, BT1, Sb, nullptr, n, 3840, 1536, 15);
            cell1_k<<<(n * HD + 255) / 256, 256, 0, stream>>>(
                ids, Sb, Wb_iou, bb_iou, Wb_f, bb_f, h_all, c_all, n, n - 1);
        } else if (n >= 512) {
            mm_k<3, 0><<<dim3(30, n / 128), 256, 0, stream>>>(
                h_all + (size_t)childoff * HD, BT1, nullptr, Sb, nullptr,
                n, 3840, 1536, 1536);
            cell1_k<<<(n * HD + 255) / 256, 256, 0, stream>>>(
                ids, Sb, Wb_iou, bb_iou, Wb_f, bb_f, h_all, c_all, n, n - 1);
        } else {
            mm_k<0, 0><<<dim3(30, (n + 127) / 128, 6), 256, 0, stream>>>(
                h_all + (size_t)childoff * HD, BT1, Sf, nullptr, nullptr,
                n, 3840, 256, 1536);
            cell1s_k<<<(n * HD + 255) / 256, 256, 0, stream>>>(
                ids, Sf, Wb_iou, bb_iou, Wb_f, bb_f, h_all, c_all, n, n - 1, 6);
        }
    }

    // ---- pass 2: 8-phase (XCD-swizzled), gather fused into GEMM ----
    mm8_k<1, 0><<<18 * 32, 512, 0, stream>>>(
        h_all, BT2, Sb, nullptr, NLEAF_OFF, 4608, 2304, 18);
    cell2_k<<<(NLEAF_OFF * HD + 255) / 256, 256, 0, stream>>>(
        ids, Sb, Wt_iou, bt_iou, Wt_f, bt_f, c_all, h3_all, NLEAF_OFF, 0);

    // ---- FFN1: 8-phase GEMM with fused bias+relu epilogue ----
    mm8_k<0, 1><<<3 * 64, 512, 0, stream>>>(
        h3_all, W1T, t1, ffn_b1, N_NODES, 768, 768, 3);

    // ---- heads: folded logits GEMM + softmax ----
    mm_k<0, 0><<<dim3(1, 128), 256, 0, stream>>>(
        t1, WcT, Lg, nullptr, nullptr, N_NODES, 128, 768, 768);
    hsm_k<<<(N_NODES + 3) / 4, 256, 0, stream>>>(
        Lg, mask, bc, (float*)d_out);
}

// Round 19
// 776.064 us; speedup vs baseline: 1.5217x; 1.0102x over previous
//
#include <hip/hip_runtime.h>
#include <hip/hip_bf16.h>

#define HD 768
#define N_NODES 16383
#define NLEAF_OFF 8191     // first leaf node index (level d=13 offset)
#define NHF 12582144       // N_NODES * HD
#define TEMP 3.0f

using bf16 = __hip_bfloat16;
typedef __attribute__((ext_vector_type(8))) short bf16x8;
typedef __attribute__((ext_vector_type(4))) float f32x4;

__device__ __forceinline__ float sigm(float x) { return 1.0f / (1.0f + __expf(-x)); }
__device__ __forceinline__ float b2f(bf16 v)   { return __bfloat162float(v); }
__device__ __forceinline__ bf16  f2b(float v)  { return __float2bfloat16(v); }

// async global->LDS, 16B per lane. LDS dest = wave-uniform base + lane*16.
__device__ __forceinline__ void gload16(const void* g, void* l) {
    __builtin_amdgcn_global_load_lds(
        (const __attribute__((address_space(1))) unsigned int*)g,
        (__attribute__((address_space(3))) unsigned int*)l, 16, 0, 0);
}

#define T1SZ 5898240      // 3840*1536
#define T2SZ 10616832     // 4608*2304
#define WSZ  589824       // 768*768

// ---------------------------------------------------------------------------
// Tiled transpose-convert (R11-proven): BT1, BT2, W1T, coalesced both sides.
// ---------------------------------------------------------------------------
__global__ __launch_bounds__(256) void tconv_k(
    const float* __restrict__ Ub_iou, const float* __restrict__ Ub_f,
    const float* __restrict__ Ut_iou, const float* __restrict__ Ut_f,
    const float* __restrict__ ffn_W1,
    bf16* __restrict__ BT1, bf16* __restrict__ BT2, bf16* __restrict__ W1T)
{
    int t = blockIdx.x;
    const float* src; bf16* dst; int C, S, kt, nt;
    if (t < 3456) {
        src = Ub_iou; dst = BT1; C = 2304; S = 1536;
        kt = t % 48; nt = t / 48;
    } else if (t < 5760) {
        int u = t - 3456; int piece = u / 576; u -= piece * 576;
        int kk = piece >> 1, l = piece & 1;
        src = Ub_f + (size_t)(kk * 2 + l) * WSZ;
        dst = BT1 + (size_t)(2304 + kk * 768) * 1536 + l * 768;
        C = 768; S = 1536; kt = u % 24; nt = u / 24;
    } else if (t < 10944) {
        int u = t - 5760;
        src = Ut_iou; dst = BT2; C = 2304; S = 2304;
        kt = u % 72; nt = u / 72;
    } else if (t < 16128) {
        int u = t - 10944; int piece = u / 576; u -= piece * 576;
        int kk = piece / 3, l = piece - kk * 3;
        src = Ut_f + (size_t)(kk * 3 + l) * WSZ;
        dst = BT2 + (size_t)(2304 + kk * 768) * 2304 + l * 768;
        C = 768; S = 2304; kt = u % 24; nt = u / 24;
    } else {
        int u = t - 16128;
        src = ffn_W1; dst = W1T; C = 768; S = 768;
        kt = u % 24; nt = u / 24;
    }
    int k0 = kt * 32, n0 = nt * 32;

    __shared__ float tl[32][33];
    int rr = threadIdx.x >> 5, c = threadIdx.x & 31;
#pragma unroll
    for (int r = 0; r < 32; r += 8)
        tl[rr + r][c] = src[(size_t)(k0 + rr + r) * C + n0 + c];
    __syncthreads();
#pragma unroll
    for (int r = 0; r < 32; r += 8)
        dst[(size_t)(n0 + rr + r) * S + k0 + c] = f2b(tl[c][rr + r]);
}

// ---------------------------------------------------------------------------
// Misc converts: WhT[128][768] + W2 bf16 cast.
// ---------------------------------------------------------------------------
#define HSZ2 98304        // 128*768
__global__ __launch_bounds__(256) void misc_k(
    const float* __restrict__ hlW, const float* __restrict__ intW,
    const float* __restrict__ actW, const float* __restrict__ W2,
    bf16* __restrict__ WhT, bf16* __restrict__ W2b)
{
    int idx = blockIdx.x * 256 + threadIdx.x;
    if (idx < HSZ2) {
        int n = idx / 768, j = idx - n * 768;
        float v = 0.f;
        if (n < 2)       v = hlW[(size_t)j * 2 + n];
        else if (n < 4)  v = intW[(size_t)j * 2 + (n - 2)];
        else if (n < 68) v = actW[(size_t)j * 64 + (n - 4)];
        WhT[idx] = f2b(v);
    } else if (idx < HSZ2 + WSZ) {
        int i2 = idx - HSZ2;
        W2b[i2] = f2b(W2[i2]);
    }
}

// Fused bias: bc[n] = sum_j b2[j]*Wh[j][n] + head_bias(n).
__global__ __launch_bounds__(128) void bck_k(
    const float* __restrict__ b2,
    const float* __restrict__ hlW, const float* __restrict__ hlb,
    const float* __restrict__ intW, const float* __restrict__ intb,
    const float* __restrict__ actW, const float* __restrict__ actb,
    float* __restrict__ bc)
{
    int n = threadIdx.x;
    float s = 0.f;
    for (int j = 0; j < 768; ++j) {
        float wh = 0.f;
        if (n < 2)       wh = hlW[(size_t)j * 2 + n];
        else if (n < 4)  wh = intW[(size_t)j * 2 + (n - 2)];
        else if (n < 68) wh = actW[(size_t)j * 64 + (n - 4)];
        s = fmaf(b2[j], wh, s);
    }
    float hb = 0.f;
    if (n < 2)       hb = hlb[n];
    else if (n < 4)  hb = intb[n - 2];
    else if (n < 68) hb = actb[n - 4];
    bc[n] = s + hb;
}

// ---------------------------------------------------------------------------
// Vocab precompute + leaf scatter (R16-proven).
// ---------------------------------------------------------------------------
__global__ __launch_bounds__(256) void vocab_k(
    const float* __restrict__ Wb, const float* __restrict__ bb,
    const float* __restrict__ Wt, const float* __restrict__ bt,
    bf16* __restrict__ Vh, bf16* __restrict__ Vc, bf16* __restrict__ Vh3)
{
    int idx = blockIdx.x * 256 + threadIdx.x;
    if (idx >= 512 * HD) return;
    int id = idx / HD, j = idx - id * HD;
    const float* w = Wb + (size_t)id * 3 * HD;
    float iv = sigm(w[j] + bb[j]);
    float ov = sigm(w[HD + j] + bb[HD + j]);
    float gv = tanhf(w[2 * HD + j] + bb[2 * HD + j]);
    float c = iv * gv;
    Vh[idx] = f2b(ov * tanhf(c));
    Vc[idx] = f2b(c);

    const float* w2 = Wt + (size_t)id * 3 * HD;
    float iv2 = sigm(w2[j] + bt[j]);
    float ov2 = sigm(w2[HD + j] + bt[HD + j]);
    float gv2 = tanhf(w2[2 * HD + j] + bt[2 * HD + j]);
    float c2 = iv2 * gv2;
    Vh3[idx] = f2b(ov2 * tanhf(c2));
}

__global__ __launch_bounds__(256) void lscat_k(
    const int* __restrict__ ids,
    const bf16* __restrict__ Vh, const bf16* __restrict__ Vc,
    const bf16* __restrict__ Vh3,
    bf16* __restrict__ h_all, bf16* __restrict__ c_all, bf16* __restrict__ h3_all)
{
    int idx = blockIdx.x * 256 + threadIdx.x;
    if (idx >= 8192 * 96) return;
    int i = idx / 96, j8 = (idx - i * 96) * 8;
    int g = NLEAF_OFF + i;
    size_t so = (size_t)ids[g] * HD + j8;
    size_t dof = (size_t)g * HD + j8;
    *(uint4*)(h_all + dof)  = *(const uint4*)(Vh + so);
    *(uint4*)(c_all + dof)  = *(const uint4*)(Vc + so);
    *(uint4*)(h3_all + dof) = *(const uint4*)(Vh3 + so);
}

// ---------------------------------------------------------------------------
// 8-phase 256x256 bf16 MFMA GEMM (T2+T3+T4+T5, T1 XCD swizzle) — R16-proven.
// EPI 0: plain bf16 store. EPI 1: bias+relu -> bf16 (FFN1).
// NOTE: only deployed where grid >= ~192 blocks (occupancy-quantized:
// 1 block/CU at 128 KB LDS — underoccupied grids pay full per-block time).
// ---------------------------------------------------------------------------
template <int GATHER, int EPI>
__global__ __launch_bounds__(512, 2) void mm8_k(
    const bf16* __restrict__ A, const bf16* __restrict__ BT,
    bf16* __restrict__ Cb, const float* __restrict__ bias,
    int M, int N, int K, int NBX)
{
    __shared__ short Al[2][16384];
    __shared__ short Bl[2][16384];

    const int tid  = threadIdx.x;
    const int lane = tid & 63;
    const int wid  = tid >> 6;
    const int wr = wid >> 2, wc = wid & 3;
    const int NT = K >> 6;

    int T = gridDim.x, L = blockIdx.x;
    int q = T >> 3, r = T & 7;
    int xcd = L & 7, i8 = L >> 3;
    int v = (xcd < r ? xcd * (q + 1) : r * (q + 1) + (xcd - r) * q) + i8;
    const int bx = v % NBX, by = v / NBX;

    const int srow = wid * 8 + (lane >> 3);
    const int scol = ((lane & 7) ^ (lane >> 3)) * 8;
    const int frow = lane & 15;
    const int fq   = lane >> 4;

    f32x4 acc[8][4] = {};

    auto stageA = [&](int t, int cr) {
        int slot = t & 1;
        int grow = by * 256 + cr + srow;
        if (grow > M - 1) grow = M - 1;
        int kb = t * 64;
        const bf16* src;
        if constexpr (GATHER) {
            int ch = kb / 768;
            int node = (ch == 0) ? grow : (2 * grow + ch);
            src = A + (size_t)node * 768 + (kb - ch * 768) + scol;
        } else {
            src = A + (size_t)grow * K + kb + scol;
        }
        gload16(src, &Al[slot][(cr + wid * 8) * 64]);
    };
    auto stageB = [&](int t, int cr) {
        int slot = t & 1;
        const bf16* src = BT + (size_t)(bx * 256 + cr + srow) * K + t * 64 + scol;
        gload16(src, &Bl[slot][(cr + wid * 8) * 64]);
    };

    stageB(0, 0);   stageB(0, 64);
    stageB(0, 128); stageB(0, 192);
    stageA(0, 0);   stageA(0, 128);
    stageA(0, 64);  stageA(0, 192);
    stageB(1, 0);   stageB(1, 64);
    stageB(1, 128); stageB(1, 192);
    stageA(1, 0);   stageA(1, 128);
    asm volatile("s_waitcnt vmcnt(6)" ::: "memory");
    __builtin_amdgcn_s_barrier();

#define PHASE(Q, STAGES, TAILWAIT)                                           \
    {                                                                        \
        bf16x8 a[2][2];                                                      \
        _Pragma("unroll")                                                    \
        for (int mq = 0; mq < 2; ++mq)                                       \
            _Pragma("unroll")                                                \
            for (int ks = 0; ks < 2; ++ks)                                   \
                a[mq][ks] = *(const bf16x8*)&Ax[                             \
                    (wr * 128 + ((Q) * 2 + mq) * 16 + frow) * 64             \
                    + (((ks * 4 + fq) ^ (frow & 7)) * 8)];                   \
        STAGES;                                                              \
        __builtin_amdgcn_s_barrier();                                        \
        asm volatile("s_waitcnt lgkmcnt(0)" ::: "memory");                   \
        __builtin_amdgcn_sched_barrier(0);                                   \
        __builtin_amdgcn_s_setprio(1);                                       \
        _Pragma("unroll")                                                    \
        for (int mq = 0; mq < 2; ++mq)                                       \
            _Pragma("unroll")                                                \
            for (int nf = 0; nf < 4; ++nf)                                   \
                _Pragma("unroll")                                            \
                for (int ks = 0; ks < 2; ++ks)                               \
                    acc[(Q) * 2 + mq][nf] =                                  \
                        __builtin_amdgcn_mfma_f32_16x16x32_bf16(             \
                            a[mq][ks], b[nf][ks], acc[(Q) * 2 + mq][nf], 0, 0, 0); \
        __builtin_amdgcn_s_setprio(0);                                       \
        TAILWAIT;                                                            \
        __builtin_amdgcn_s_barrier();                                        \
    }

    for (int t = 0; t < NT; ++t) {
        short* Ax = Al[t & 1];
        short* Bx = Bl[t & 1];
        bf16x8 b[4][2];
#pragma unroll
        for (int nf = 0; nf < 4; ++nf)
#pragma unroll
            for (int ks = 0; ks < 2; ++ks)
                b[nf][ks] = *(const bf16x8*)&Bx[
                    (wc * 64 + nf * 16 + frow) * 64
                    + (((ks * 4 + fq) ^ (frow & 7)) * 8)];

        PHASE(0,
              { if (t + 1 < NT) { stageA(t + 1, 64); stageA(t + 1, 192); } },
              {})
        PHASE(1,
              { if (t + 2 < NT) { stageB(t + 2, 0); stageB(t + 2, 64); } },
              {})
        PHASE(2,
              { if (t + 2 < NT) { stageB(t + 2, 128); stageB(t + 2, 192); } },
              {})
        PHASE(3,
              { if (t + 2 < NT) { stageA(t + 2, 0); stageA(t + 2, 128); } },
              {
                  if (t + 2 < NT) asm volatile("s_waitcnt vmcnt(6)" ::: "memory");
                  else            asm volatile("s_waitcnt vmcnt(0)" ::: "memory");
              })
    }
#undef PHASE

#pragma unroll
    for (int mf = 0; mf < 8; ++mf) {
#pragma unroll
        for (int r2 = 0; r2 < 4; ++r2) {
            int row = by * 256 + wr * 128 + mf * 16 + (lane >> 4) * 4 + r2;
            if (row >= M) continue;
#pragma unroll
            for (int nf = 0; nf < 4; ++nf) {
                int col = bx * 256 + wc * 64 + nf * 16 + (lane & 15);
                float vv = acc[mf][nf][r2];
                if constexpr (EPI == 1) vv = fmaxf(vv + bias[col], 0.f);
                Cb[(size_t)row * N + col] = f2b(vv);
            }
        }
    }
}

// ---------------------------------------------------------------------------
// bf16 MFMA GEMM (R8-proven m97 structure) with K-split support.
// ---------------------------------------------------------------------------
template <int EPI, int GATHER>
__global__ __launch_bounds__(256) void mm_k(
    const bf16* __restrict__ A, const bf16* __restrict__ BT,
    float* __restrict__ Cf, bf16* __restrict__ Cb,
    const float* __restrict__ bias,
    int M, int N, int Kc, int Kfull)
{
    __shared__ short As[128 * 32];
    __shared__ short Bs[128 * 32];

    int tid  = threadIdx.x;
    int lane = tid & 63;
    int wave = tid >> 6;
    int wr = wave >> 1, wc = wave & 1;
    int bx = blockIdx.x, by = blockIdx.y;
    int colbase = blockIdx.z * Kc;
    if constexpr (EPI == 0) Cf += (size_t)blockIdx.z * ((size_t)M * N);

    f32x4 acc[4][4] = {};

    int sr  = lane >> 2;
    int sc8 = (lane & 3) * 8;
    int arow0 = by * 128 + wave * 16 + sr;
    int arow1 = arow0 + 64;
    if (arow0 > M - 1) arow0 = M - 1;
    if (arow1 > M - 1) arow1 = M - 1;
    const bf16* gA0 = A + (size_t)arow0 * Kfull + colbase + sc8;
    const bf16* gA1 = A + (size_t)arow1 * Kfull + colbase + sc8;
    const bf16* gB0 = BT + (size_t)(bx * 128 + wave * 16 + sr) * Kfull + colbase + sc8;
    const bf16* gB1 = BT + (size_t)(bx * 128 + wave * 16 + sr + 64) * Kfull + colbase + sc8;
    short* lA0 = As + wave * 512;
    short* lA1 = As + wave * 512 + 2048;
    short* lB0 = Bs + wave * 512;
    short* lB1 = Bs + wave * 512 + 2048;

    int fr = lane & 15;
    int fk = (lane >> 4) << 3;
    const short* pAf = As + (wr * 64 + fr) * 32 + fk;
    const short* pBf = Bs + (wc * 64 + fr) * 32 + fk;

    for (int kt = 0; kt < Kc; kt += 32) {
        if constexpr (GATHER) {
            int abs0 = colbase + kt;
            int ch = (abs0 >= 768) + (abs0 >= 1536);
            int col = abs0 - ch * 768 + sc8;
            int n0 = (ch == 0) ? arow0 : (2 * arow0 + ch);
            int n1 = (ch == 0) ? arow1 : (2 * arow1 + ch);
            gload16(A + (size_t)n0 * HD + col, lA0);
            gload16(A + (size_t)n1 * HD + col, lA1);
        } else {
            gload16(gA0 + kt, lA0);
            gload16(gA1 + kt, lA1);
        }
        gload16(gB0 + kt, lB0);
        gload16(gB1 + kt, lB1);
        __syncthreads();

        bf16x8 a[4], b[4];
#pragma unroll
        for (int m = 0; m < 4; m++) a[m] = *(const bf16x8*)(pAf + m * 512);
#pragma unroll
        for (int n = 0; n < 4; n++) b[n] = *(const bf16x8*)(pBf + n * 512);
#pragma unroll
        for (int m = 0; m < 4; m++)
#pragma unroll
            for (int n = 0; n < 4; n++)
                acc[m][n] = __builtin_amdgcn_mfma_f32_16x16x32_bf16(
                    a[m], b[n], acc[m][n], 0, 0, 0);
        __syncthreads();
    }

    int rbase = by * 128 + wr * 64 + ((lane >> 4) << 2);
    int cbase = bx * 128 + wc * 64 + fr;
#pragma unroll
    for (int m = 0; m < 4; m++) {
#pragma unroll
        for (int r = 0; r < 4; r++) {
            int row = rbase + m * 16 + r;
            if (row >= M) continue;
#pragma unroll
            for (int n = 0; n < 4; n++) {
                int col = cbase + n * 16;
                float v = acc[m][n][r];
                if constexpr (EPI == 1) {
                    v = fmaxf(v + bias[col], 0.f);
                    Cb[(size_t)row * N + col] = f2b(v);
                } else if constexpr (EPI == 3) {
                    Cb[(size_t)row * N + col] = f2b(v);
                } else {
                    Cf[(size_t)row * N + col] = v;
                }
            }
        }
    }
}

// ---------------------------------------------------------------------------
// Pass-1 cell (R8 scalar form): bf16 S(m x 3840) -> bf16 h,c.
// ---------------------------------------------------------------------------
__global__ __launch_bounds__(256) void cell1_k(
    const int* __restrict__ ids, const bf16* __restrict__ S,
    const float* __restrict__ Wiou, const float* __restrict__ biou,
    const float* __restrict__ Wf, const float* __restrict__ bfv,
    bf16* __restrict__ h_all, bf16* __restrict__ c_all,
    int m, int offAbs)
{
    int idx = blockIdx.x * blockDim.x + threadIdx.x;
    if (idx >= m * HD) return;
    int i = idx / HD, j = idx - i * HD;
    int g = offAbs + i;
    int id = ids[g];
    const bf16* s = S + (size_t)i * 3840;
    const float* w = Wiou + (size_t)id * 2304;
    float iv = sigm(b2f(s[j]) + w[j] + biou[j]);
    float ov = sigm(b2f(s[HD + j]) + w[HD + j] + biou[HD + j]);
    float gv = tanhf(b2f(s[2 * HD + j]) + w[2 * HD + j] + biou[2 * HD + j]);
    float xf = Wf[(size_t)id * HD + j] + bfv[j];
    float f0 = sigm(b2f(s[3 * HD + j]) + xf);
    float f1 = sigm(b2f(s[4 * HD + j]) + xf);
    float c = iv * gv
            + f0 * b2f(c_all[(size_t)(2 * g + 1) * HD + j])
            + f1 * b2f(c_all[(size_t)(2 * g + 2) * HD + j]);
    h_all[(size_t)g * HD + j] = f2b(ov * tanhf(c));
    c_all[(size_t)g * HD + j] = f2b(c);
}

// ---------------------------------------------------------------------------
// Pass-1 cell, split-K variant: sums KS fp32 partials Sf[z][m][3840].
// ---------------------------------------------------------------------------
__global__ __launch_bounds__(256) void cell1s_k(
    const int* __restrict__ ids, const float* __restrict__ Sf,
    const float* __restrict__ Wiou, const float* __restrict__ biou,
    const float* __restrict__ Wf, const float* __restrict__ bfv,
    bf16* __restrict__ h_all, bf16* __restrict__ c_all,
    int m, int offAbs, int KS)
{
    int idx = blockIdx.x * blockDim.x + threadIdx.x;
    if (idx >= m * HD) return;
    int i = idx / HD, j = idx - i * HD;
    int g = offAbs + i;
    int id = ids[g];
    const float* s = Sf + (size_t)i * 3840;
    size_t zs = (size_t)m * 3840;
    float si = 0.f, so = 0.f, su = 0.f, p0 = 0.f, p1 = 0.f;
    for (int z = 0; z < KS; ++z) {
        const float* sz = s + z * zs;
        si += sz[j];
        so += sz[HD + j];
        su += sz[2 * HD + j];
        p0 += sz[3 * HD + j];
        p1 += sz[4 * HD + j];
    }
    const float* w = Wiou + (size_t)id * 2304;
    float iv = sigm(si + w[j] + biou[j]);
    float ov = sigm(so + w[HD + j] + biou[HD + j]);
    float gv = tanhf(su + w[2 * HD + j] + biou[2 * HD + j]);
    float xf = Wf[(size_t)id * HD + j] + bfv[j];
    float f0 = sigm(p0 + xf);
    float f1 = sigm(p1 + xf);
    float c = iv * gv
            + f0 * b2f(c_all[(size_t)(2 * g + 1) * HD + j])
            + f1 * b2f(c_all[(size_t)(2 * g + 2) * HD + j]);
    h_all[(size_t)g * HD + j] = f2b(ov * tanhf(c));
    c_all[(size_t)g * HD + j] = f2b(c);
}

// ---------------------------------------------------------------------------
// Pass-2 cell (R8 scalar form): bf16 S(m x 4608) -> bf16 h3.
// ---------------------------------------------------------------------------
__global__ __launch_bounds__(256) void cell2_k(
    const int* __restrict__ ids, const bf16* __restrict__ S,
    const float* __restrict__ Wiou, const float* __restrict__ biou,
    const float* __restrict__ Wf, const float* __restrict__ bfv,
    const bf16* __restrict__ c_all, bf16* __restrict__ h3_all,
    int m, int g0)
{
    int idx = blockIdx.x * blockDim.x + threadIdx.x;
    if (idx >= m * HD) return;
    int i = idx / HD, j = idx - i * HD;
    int g = g0 + i;
    int id = ids[g];
    const bf16* s = S + (size_t)i * 4608;
    const float* w = Wiou + (size_t)id * 2304;
    float iv = sigm(b2f(s[j]) + w[j] + biou[j]);
    float ov = sigm(b2f(s[HD + j]) + w[HD + j] + biou[HD + j]);
    float gv = tanhf(b2f(s[2 * HD + j]) + w[2 * HD + j] + biou[2 * HD + j]);
    float xf = Wf[(size_t)id * HD + j] + bfv[j];
    float f0 = sigm(b2f(s[3 * HD + j]) + xf);
    float f1 = sigm(b2f(s[4 * HD + j]) + xf);
    float f2 = sigm(b2f(s[5 * HD + j]) + xf);
    float c = iv * gv
            + f0 * b2f(c_all[(size_t)g * HD + j])
            + f1 * b2f(c_all[(size_t)(2 * g + 1) * HD + j])
            + f2 * b2f(c_all[(size_t)(2 * g + 2) * HD + j]);
    h3_all[(size_t)g * HD + j] = f2b(ov * tanhf(c));
}

// ---------------------------------------------------------------------------
// Head softmaxes from logits L[g][128]; bc holds fused biases. fp32 out.
// ---------------------------------------------------------------------------
__global__ __launch_bounds__(256) void hsm_k(
    const float* __restrict__ L, const int* __restrict__ mask,
    const float* __restrict__ bc, float* __restrict__ out)
{
    int g = blockIdx.x * 4 + (threadIdx.x >> 6);
    if (g >= N_NODES) return;
    int t = threadIdx.x & 63;
    const float* lr = L + (size_t)g * 128;

    bool on = mask[(size_t)g * 64 + t] > 0;
    float x = (lr[4 + t] + bc[4 + t]) * (1.0f / TEMP);
    float mx = on ? x : -INFINITY;
#pragma unroll
    for (int o = 32; o; o >>= 1) mx = fmaxf(mx, __shfl_xor(mx, o));
    float e = on ? __expf(x - mx) : 0.0f;
    float s = e;
#pragma unroll
    for (int o = 32; o; o >>= 1) s += __shfl_xor(s, o);
    float r = (s > 0.f) ? e / s : (1.0f / 64.0f);
    out[(size_t)g * 68 + 4 + t] = r;

    if (t == 0) {
        float a = (lr[0] + bc[0]) * (1.0f / TEMP);
        float b = (lr[1] + bc[1]) * (1.0f / TEMP);
        float m2 = fmaxf(a, b);
        float e0 = __expf(a - m2), e1 = __expf(b - m2);
        out[(size_t)g * 68 + 0] = e0 / (e0 + e1);
        out[(size_t)g * 68 + 1] = e1 / (e0 + e1);
    } else if (t == 1) {
        float a = (lr[2] + bc[2]) * (1.0f / TEMP);
        float b = (lr[3] + bc[3]) * (1.0f / TEMP);
        float m2 = fmaxf(a, b);
        float e0 = __expf(a - m2), e1 = __expf(b - m2);
        out[(size_t)g * 68 + 2] = e0 / (e0 + e1);
        out[(size_t)g * 68 + 3] = e1 / (e0 + e1);
    }
}

// ---------------------------------------------------------------------------
extern "C" void kernel_launch(void* const* d_in, const int* in_sizes, int n_in,
                              void* d_out, int out_size, void* d_ws, size_t ws_size,
                              hipStream_t stream)
{
    const int*   ids     = (const int*)d_in[0];
    const int*   mask    = (const int*)d_in[1];
    const float* Wb_iou  = (const float*)d_in[2];
    const float* Ub_iou  = (const float*)d_in[3];
    const float* bb_iou  = (const float*)d_in[4];
    const float* Wb_f    = (const float*)d_in[5];
    const float* Ub_f    = (const float*)d_in[6];
    const float* bb_f    = (const float*)d_in[7];
    const float* Wt_iou  = (const float*)d_in[8];
    const float* Ut_iou  = (const float*)d_in[9];
    const float* bt_iou  = (const float*)d_in[10];
    const float* Wt_f    = (const float*)d_in[11];
    const float* Ut_f    = (const float*)d_in[12];
    const float* bt_f    = (const float*)d_in[13];
    const float* ffn_W1  = (const float*)d_in[14];
    const float* ffn_b1  = (const float*)d_in[15];
    const float* ffn_W2  = (const float*)d_in[16];
    const float* ffn_b2  = (const float*)d_in[17];
    const float* hl_W    = (const float*)d_in[18];
    const float* hl_b    = (const float*)d_in[19];
    const float* int_W   = (const float*)d_in[20];
    const float* int_b   = (const float*)d_in[21];
    const float* act_W   = (const float*)d_in[22];
    const float* act_b   = (const float*)d_in[23];

    // ---- workspace layout ----
    char* p = (char*)d_ws;
    bf16* h_all  = (bf16*)p; p += (size_t)NHF * 2;
    bf16* c_all  = (bf16*)p; p += (size_t)NHF * 2;
    bf16* h3_all = (bf16*)p; p += (size_t)NHF * 2;
    bf16* BT1 = (bf16*)p; p += (size_t)T1SZ * 2;
    bf16* BT2 = (bf16*)p; p += (size_t)T2SZ * 2;
    bf16* W1T = (bf16*)p; p += (size_t)WSZ * 2;
    bf16* WcT = (bf16*)p; p += (size_t)128 * 768 * 2;
    bf16* WhT = (bf16*)p; p += (size_t)HSZ2 * 2;
    bf16* W2b = (bf16*)p; p += (size_t)WSZ * 2;
    bf16* Vh  = (bf16*)p; p += (size_t)512 * HD * 2;
    bf16* Vc  = (bf16*)p; p += (size_t)512 * HD * 2;
    bf16* Vh3 = (bf16*)p; p += (size_t)512 * HD * 2;
    float* bc = (float*)p; p += 512;
    bf16* Sb  = (bf16*)p;              // bf16 S: up to 8191 x 4608 = 75.5 MB
    float* Sf = (float*)Sb;            // fp32 split-K partials (tail levels)
    bf16* t1  = c_all;                 // FFN hidden aliases dead c
    float* Lg = (float*)h3_all;        // head logits alias h3 (dead after FFN1)

    // ---- weight conversions (coalesced) ----
    tconv_k<<<16704, 256, 0, stream>>>(
        Ub_iou, Ub_f, Ut_iou, Ut_f, ffn_W1, BT1, BT2, W1T);
    misc_k<<<(HSZ2 + WSZ + 255) / 256, 256, 0, stream>>>(
        hl_W, int_W, act_W, ffn_W2, WhT, W2b);
    bck_k<<<1, 128, 0, stream>>>(
        ffn_b2, hl_W, hl_b, int_W, int_b, act_W, act_b, bc);
    mm_k<3, 0><<<dim3(6, 1), 256, 0, stream>>>(
        WhT, W2b, nullptr, WcT, nullptr, 128, 768, 768, 768);

    // ---- leaves: vocab precompute + scatter ----
    vocab_k<<<(512 * HD + 255) / 256, 256, 0, stream>>>(
        Wb_iou, bb_iou, Wt_iou, bt_iou, Vh, Vc, Vh3);
    lscat_k<<<(8192 * 96 + 255) / 256, 256, 0, stream>>>(
        ids, Vh, Vc, Vh3, h_all, c_all, h3_all);

    // ---- pass 1: mm8 only where grid fills the GPU (d=12); mm_k 512-2048;
    //      split-K tail below 512 ----
    for (int d = 12; d >= 0; --d) {
        int n = 1 << d;
        int childoff = 2 * n - 1;
        if (n >= 4096) {
            mm8_k<0, 0><<<15 * (n / 256), 512, 0, stream>>>(
                h_all + (size_t)childoff * HD, BT1, Sb, nullptr, n, 3840, 1536, 15);
            cell1_k<<<(n * HD + 255) / 256, 256, 0, stream>>>(
                ids, Sb, Wb_iou, bb_iou, Wb_f, bb_f, h_all, c_all, n, n - 1);
        } else if (n >= 512) {
            mm_k<3, 0><<<dim3(30, n / 128), 256, 0, stream>>>(
                h_all + (size_t)childoff * HD, BT1, nullptr, Sb, nullptr,
                n, 3840, 1536, 1536);
            cell1_k<<<(n * HD + 255) / 256, 256, 0, stream>>>(
                ids, Sb, Wb_iou, bb_iou, Wb_f, bb_f, h_all, c_all, n, n - 1);
        } else {
            mm_k<0, 0><<<dim3(30, (n + 127) / 128, 6), 256, 0, stream>>>(
                h_all + (size_t)childoff * HD, BT1, Sf, nullptr, nullptr,
                n, 3840, 256, 1536);
            cell1s_k<<<(n * HD + 255) / 256, 256, 0, stream>>>(
                ids, Sf, Wb_iou, bb_iou, Wb_f, bb_f, h_all, c_all, n, n - 1, 6);
        }
    }

    // ---- pass 2: 8-phase (XCD-swizzled), gather fused into GEMM ----
    mm8_k<1, 0><<<18 * 32, 512, 0, stream>>>(
        h_all, BT2, Sb, nullptr, NLEAF_OFF, 4608, 2304, 18);
    cell2_k<<<(NLEAF_OFF * HD + 255) / 256, 256, 0, stream>>>(
        ids, Sb, Wt_iou, bt_iou, Wt_f, bt_f, c_all, h3_all, NLEAF_OFF, 0);

    // ---- FFN1: 8-phase GEMM with fused bias+relu epilogue ----
    mm8_k<0, 1><<<3 * 64, 512, 0, stream>>>(
        h3_all, W1T, t1, ffn_b1, N_NODES, 768, 768, 3);

    // ---- heads: folded logits GEMM + softmax ----
    mm_k<0, 0><<<dim3(1, 128), 256, 0, stream>>>(
        t1, WcT, Lg, nullptr, nullptr, N_NODES, 128, 768, 768);
    hsm_k<<<(N_NODES + 3) / 4, 256, 0, stream>>>(
        Lg, mask, bc, (float*)d_out);
}